// Round 1
// baseline (38.805 us; speedup 1.0000x reference)
//
#include <hip/hip_runtime.h>

// ButterflyConv2d: 4 fused grouped-1x1-conv rounds with butterfly perms.
// x: [32, 256, 56, 56] f32, w_r: [64, 4, 4] f32, out: [32, 256, 56, 56] f32.
//
// Digit view: channel c = (d3,d2,d1,d0) base-4. perm0: swap d1,d0.
// perm1: (d3,d2,d1,d0)->(d3,d1,d0,d2). perm2: ->(d2,d1,d0,d3).
// Stage A (rounds 0+1) closes over sets {d3=u,d2=v}; stage B (rounds 2+3)
// closes over round-1-output sets {d3=e,d0=f}. One LDS exchange total.

#define NPIX_TILE 64
#define NTILES_PER_IMG 49   // 56*56 / 64
#define HW 3136             // 56*56

__global__ __launch_bounds__(1024, 4)
void butterfly_fused_kernel(const float* __restrict__ x,
                            const float* __restrict__ w0,
                            const float* __restrict__ w1,
                            const float* __restrict__ w2,
                            const float* __restrict__ w3,
                            float* __restrict__ out) {
    __shared__ float buf[256][NPIX_TILE];   // 64 KB: [channel][pixel]

    const int p   = threadIdx.x & 63;                                   // lane = pixel
    const int set = __builtin_amdgcn_readfirstlane((int)(threadIdx.x >> 6)); // 0..15, wave-uniform
    const int img  = blockIdx.x / NTILES_PER_IMG;
    const int tile = blockIdx.x % NTILES_PER_IMG;
    const int base = img * 256 * HW + tile * NPIX_TILE + p;             // fits in int

    // ---------------- Stage A: rounds 0 & 1, set (u,v) = (d3,d2) ----------------
    const int u = set >> 2, v = set & 3;

    // load 16 input channels (u,v,i,j), coalesced across lanes (pixel-contiguous)
    float xr[16];
#pragma unroll
    for (int i = 0; i < 4; ++i)
#pragma unroll
        for (int j = 0; j < 4; ++j) {
            const int c = (u << 6) | (v << 4) | (i << 2) | j;
            xr[4 * i + j] = x[base + c * HW];
        }

    // round 0: group (u,v,i): b0[4i+o] = sum_j w0[g][o][j] * xr[4i+j]
    float b0[16];
#pragma unroll
    for (int i = 0; i < 4; ++i) {
        const float* wg = w0 + (((u << 4) | (v << 2) | i) << 4);
#pragma unroll
        for (int o = 0; o < 4; ++o) {
            float acc = wg[o * 4 + 0] * xr[4 * i + 0];
            acc += wg[o * 4 + 1] * xr[4 * i + 1];
            acc += wg[o * 4 + 2] * xr[4 * i + 2];
            acc += wg[o * 4 + 3] * xr[4 * i + 3];
            b0[4 * i + o] = acc;
        }
    }

    // round 1 (inputs via perm0 = swap d1,d0, all within this set):
    // b1[4*d1+o] = sum_i w1[(u,v,d1)][o][i] * b0[4i+d1]
    float b1[16];
#pragma unroll
    for (int d1 = 0; d1 < 4; ++d1) {
        const float* wg = w1 + (((u << 4) | (v << 2) | d1) << 4);
#pragma unroll
        for (int o = 0; o < 4; ++o) {
            float acc = wg[o * 4 + 0] * b0[0 + d1];
            acc += wg[o * 4 + 1] * b0[4 + d1];
            acc += wg[o * 4 + 2] * b0[8 + d1];
            acc += wg[o * 4 + 3] * b0[12 + d1];
            b1[4 * d1 + o] = acc;
        }
    }

    // store round-1 output channel (u,v,d1,o) = (set<<4)|k ; lane=pixel -> conflict-free
#pragma unroll
    for (int k = 0; k < 16; ++k)
        buf[(set << 4) | k][p] = b1[k];

    __syncthreads();

    // ---------------- Stage B: rounds 2 & 3, set (e,f) -------------------------
    const int e = u, f = v;

    // gather round-1 outputs: input chan (e,f,i,i2) lives at slot (e,i,i2,f)
    float yr[16];
#pragma unroll
    for (int i = 0; i < 4; ++i)
#pragma unroll
        for (int i2 = 0; i2 < 4; ++i2)
            yr[4 * i + i2] = buf[(e << 6) | (i << 4) | (i2 << 2) | f][p];

    // round 2: group (e,f,i): b2[4i+o] = sum_i2 w2[g][o][i2] * yr[4i+i2]
    float b2[16];
#pragma unroll
    for (int i = 0; i < 4; ++i) {
        const float* wg = w2 + (((e << 4) | (f << 2) | i) << 4);
#pragma unroll
        for (int o = 0; o < 4; ++o) {
            float acc = wg[o * 4 + 0] * yr[4 * i + 0];
            acc += wg[o * 4 + 1] * yr[4 * i + 1];
            acc += wg[o * 4 + 2] * yr[4 * i + 2];
            acc += wg[o * 4 + 3] * yr[4 * i + 3];
            b2[4 * i + o] = acc;
        }
    }

    // round 3: output chan (g2,e,f,o), group (g2,e,f), input i -> b2[4i+g2]
#pragma unroll
    for (int g2 = 0; g2 < 4; ++g2) {
        const float* wg = w3 + (((g2 << 4) | (e << 2) | f) << 4);
#pragma unroll
        for (int o = 0; o < 4; ++o) {
            float acc = wg[o * 4 + 0] * b2[0 + g2];
            acc += wg[o * 4 + 1] * b2[4 + g2];
            acc += wg[o * 4 + 2] * b2[8 + g2];
            acc += wg[o * 4 + 3] * b2[12 + g2];
            const int c = (g2 << 6) | (e << 4) | (f << 2) | o;
            out[base + c * HW] = acc;  // coalesced across lanes
        }
    }
}

extern "C" void kernel_launch(void* const* d_in, const int* in_sizes, int n_in,
                              void* d_out, int out_size, void* d_ws, size_t ws_size,
                              hipStream_t stream) {
    const float* x  = (const float*)d_in[0];
    const float* w0 = (const float*)d_in[1];
    const float* w1 = (const float*)d_in[2];
    const float* w2 = (const float*)d_in[3];
    const float* w3 = (const float*)d_in[4];
    float* out = (float*)d_out;

    dim3 grid(32 * NTILES_PER_IMG);   // 1568 blocks
    dim3 block(1024);                 // 16 waves: one 16-channel set per wave
    butterfly_fused_kernel<<<grid, block, 0, stream>>>(x, w0, w1, w2, w3, out);
}

// Round 3
// 38.796 us; speedup vs baseline: 1.0002x; 1.0002x over previous
//
#include <hip/hip_runtime.h>

// ButterflyConv2d: 4 fused grouped-1x1-conv rounds with butterfly perms.
// v2b: float4-vectorized (native ext_vector_type for nontemporal stores),
// e-decomposed (exchange is block-diagonal in d3=e), wave-uniform weights.
//
// x: [32, 256, 56, 56] f32, w_r: [64, 4, 4] f32, out: [32, 256, 56, 56] f32.
// Channel c = (d3,d2,d1,d0) base-4. Stage A (rounds 0+1) per set (u=e, v);
// stage B (rounds 2+3) per set (e,f) reads only stage-A outputs with u=e.
// Block = one (img, e, 256-px tile): 4 waves, wave = one set; thread = 4 px.

#define HW 3136          // 56*56
#define TILE_PX 256
#define NT 13            // ceil(3136 / 256)

typedef float f32x4 __attribute__((ext_vector_type(4)));

__device__ __forceinline__ void fma4(f32x4& acc, float s, const f32x4& a) {
    acc = s * a + acc;   // element-wise fma on native vector
}

__global__ __launch_bounds__(256, 2)
void butterfly_fused_v2(const float* __restrict__ x,
                        const float* __restrict__ w0,
                        const float* __restrict__ w1,
                        const float* __restrict__ w2,
                        const float* __restrict__ w3,
                        float* __restrict__ out) {
    __shared__ float buf[64 * TILE_PX];   // 64 KB: [local channel][pixel]

    const int l  = threadIdx.x & 63;                                        // lane
    const int wv = __builtin_amdgcn_readfirstlane((int)(threadIdx.x >> 6)); // 0..3 set
    const int bid  = blockIdx.x;
    const int tile = bid % NT;
    const int rem  = bid / NT;
    const int e    = rem & 3;
    const int img  = rem >> 2;

    const int pix  = tile * TILE_PX + 4 * l;
    const bool ok  = pix < HW;
    const int pixc = ok ? pix : 0;                 // clamp loads in partial tile
    const int ibase = img * 256 * HW + pixc;       // input base (clamped)
    const int obase = img * 256 * HW + pix;        // output base (guarded)

    // ---------------- Stage A: rounds 0 & 1, set (u=e, v=wv) ----------------
    // load 16 input channels (e,wv,i,j) as f32x4 (coalesced: lane stride 16B)
    f32x4 xr[16];
#pragma unroll
    for (int i = 0; i < 4; ++i)
#pragma unroll
        for (int j = 0; j < 4; ++j) {
            const int c = (e << 6) | (wv << 4) | (i << 2) | j;
            xr[4 * i + j] = *reinterpret_cast<const f32x4*>(x + ibase + c * HW);
        }

    // round 0: group (e,wv,i): b0[4i+o] = sum_j w0[g][o][j] * xr[4i+j]
    f32x4 b0[16];
#pragma unroll
    for (int i = 0; i < 4; ++i) {
        const float* wg = w0 + (((e << 4) | (wv << 2) | i) << 4);
#pragma unroll
        for (int o = 0; o < 4; ++o) {
            f32x4 acc = wg[o * 4 + 0] * xr[4 * i + 0];
            fma4(acc, wg[o * 4 + 1], xr[4 * i + 1]);
            fma4(acc, wg[o * 4 + 2], xr[4 * i + 2]);
            fma4(acc, wg[o * 4 + 3], xr[4 * i + 3]);
            b0[4 * i + o] = acc;
        }
    }

    // round 1 (perm0 = swap d1,d0): b1[4*d1+o] = sum_i w1[(e,wv,d1)][o][i] * b0[4i+d1]
    // store to LDS at local channel lc = (wv,d1,o)
#pragma unroll
    for (int d1 = 0; d1 < 4; ++d1) {
        const float* wg = w1 + (((e << 4) | (wv << 2) | d1) << 4);
#pragma unroll
        for (int o = 0; o < 4; ++o) {
            f32x4 acc = wg[o * 4 + 0] * b0[0 + d1];
            fma4(acc, wg[o * 4 + 1], b0[4 + d1]);
            fma4(acc, wg[o * 4 + 2], b0[8 + d1]);
            fma4(acc, wg[o * 4 + 3], b0[12 + d1]);
            const int lc = (wv << 4) | (d1 << 2) | o;
            *reinterpret_cast<f32x4*>(buf + lc * TILE_PX + 4 * l) = acc;
        }
    }

    __syncthreads();

    // ---------------- Stage B: rounds 2 & 3, set (e, f=wv) ----------------
    // gather round-1 outputs: channel (e,i,i2,f) is at local slot (i,i2,f)
    const int f = wv;
    f32x4 yr[16];
#pragma unroll
    for (int i = 0; i < 4; ++i)
#pragma unroll
        for (int i2 = 0; i2 < 4; ++i2) {
            const int lc = (i << 4) | (i2 << 2) | f;
            yr[4 * i + i2] = *reinterpret_cast<const f32x4*>(buf + lc * TILE_PX + 4 * l);
        }

    // round 2: group (e,f,i): b2[4i+o] = sum_i2 w2[g][o][i2] * yr[4i+i2]
    f32x4 b2[16];
#pragma unroll
    for (int i = 0; i < 4; ++i) {
        const float* wg = w2 + (((e << 4) | (f << 2) | i) << 4);
#pragma unroll
        for (int o = 0; o < 4; ++o) {
            f32x4 acc = wg[o * 4 + 0] * yr[4 * i + 0];
            fma4(acc, wg[o * 4 + 1], yr[4 * i + 1]);
            fma4(acc, wg[o * 4 + 2], yr[4 * i + 2]);
            fma4(acc, wg[o * 4 + 3], yr[4 * i + 3]);
            b2[4 * i + o] = acc;
        }
    }

    // round 3: out chan (g2,e,f,o), group (g2,e,f), input i -> b2[4i+g2]
#pragma unroll
    for (int g2 = 0; g2 < 4; ++g2) {
        const float* wg = w3 + (((g2 << 4) | (e << 2) | f) << 4);
#pragma unroll
        for (int o = 0; o < 4; ++o) {
            f32x4 acc = wg[o * 4 + 0] * b2[0 + g2];
            fma4(acc, wg[o * 4 + 1], b2[4 + g2]);
            fma4(acc, wg[o * 4 + 2], b2[8 + g2]);
            fma4(acc, wg[o * 4 + 3], b2[12 + g2]);
            if (ok) {
                const int c = (g2 << 6) | (e << 4) | (f << 2) | o;
                __builtin_nontemporal_store(acc,
                    reinterpret_cast<f32x4*>(out + obase + c * HW));
            }
        }
    }
}

extern "C" void kernel_launch(void* const* d_in, const int* in_sizes, int n_in,
                              void* d_out, int out_size, void* d_ws, size_t ws_size,
                              hipStream_t stream) {
    const float* x  = (const float*)d_in[0];
    const float* w0 = (const float*)d_in[1];
    const float* w1 = (const float*)d_in[2];
    const float* w2 = (const float*)d_in[3];
    const float* w3 = (const float*)d_in[4];
    float* out = (float*)d_out;

    dim3 grid(32 * 4 * NT);   // (img, e, tile) = 1664 blocks
    dim3 block(256);          // 4 waves: one 16-channel set per wave
    butterfly_fused_v2<<<grid, block, 0, stream>>>(x, w0, w1, w2, w3, out);
}